// Round 1
// baseline (434.287 us; speedup 1.0000x reference)
//
#include <hip/hip_runtime.h>

// 23-qubit batched complex state, 2x2 complex gate on qubit 12.
// DIM = 2^23, BATCH = 4. Axis 12 stride (in basis index) = 2^10.
// out = stack([re, im]) of shape (2, DIM, BATCH), fp32.
//
// Memory-bound: 256 MiB read + 256 MiB write, zero reuse -> HBM roofline ~85us.

#define NQ 23
#define DIMQ (1 << NQ)
#define BATCH 4
#define TBIT 10  // 2^(23-1-12)

__global__ __launch_bounds__(256) void gate_q12_kernel(
    const float* __restrict__ sre, const float* __restrict__ sim,
    const float* __restrict__ mre, const float* __restrict__ mim,
    float* __restrict__ out)
{
    const unsigned p = blockIdx.x * blockDim.x + threadIdx.x;  // pair idx, < DIMQ/2
    const unsigned low  = p & ((1u << TBIT) - 1u);
    const unsigned high = p >> TBIT;
    const unsigned b0 = (high << (TBIT + 1)) | low;   // target bit = 0
    const unsigned b1 = b0 | (1u << TBIT);            // target bit = 1

    const float4 r0 = *(const float4*)(sre + (size_t)b0 * BATCH);
    const float4 r1 = *(const float4*)(sre + (size_t)b1 * BATCH);
    const float4 i0 = *(const float4*)(sim + (size_t)b0 * BATCH);
    const float4 i1 = *(const float4*)(sim + (size_t)b1 * BATCH);

    // 2x2 gate coefficients (row-major): m[r][c]
    const float mr00 = mre[0], mr01 = mre[1], mr10 = mre[2], mr11 = mre[3];
    const float mi00 = mim[0], mi01 = mim[1], mi10 = mim[2], mi11 = mim[3];

    float4 or0, or1, oi0, oi1;
#define COMP(c)                                                      \
    or0.c = mr00*r0.c + mr01*r1.c - (mi00*i0.c + mi01*i1.c);         \
    oi0.c = mr00*i0.c + mr01*i1.c + (mi00*r0.c + mi01*r1.c);         \
    or1.c = mr10*r0.c + mr11*r1.c - (mi10*i0.c + mi11*i1.c);         \
    oi1.c = mr10*i0.c + mr11*i1.c + (mi10*r0.c + mi11*r1.c);
    COMP(x) COMP(y) COMP(z) COMP(w)
#undef COMP

    float* ore = out;                                   // out[0] = real plane
    float* oim = out + (size_t)DIMQ * BATCH;            // out[1] = imag plane
    *(float4*)(ore + (size_t)b0 * BATCH) = or0;
    *(float4*)(ore + (size_t)b1 * BATCH) = or1;
    *(float4*)(oim + (size_t)b0 * BATCH) = oi0;
    *(float4*)(oim + (size_t)b1 * BATCH) = oi1;
}

extern "C" void kernel_launch(void* const* d_in, const int* in_sizes, int n_in,
                              void* d_out, int out_size, void* d_ws, size_t ws_size,
                              hipStream_t stream) {
    const float* sre = (const float*)d_in[0];
    const float* sim = (const float*)d_in[1];
    const float* mre = (const float*)d_in[2];
    const float* mim = (const float*)d_in[3];
    float* out = (float*)d_out;

    const int pairs = DIMQ / 2;           // 4,194,304
    dim3 block(256);
    dim3 grid(pairs / 256);               // 16384 blocks
    gate_q12_kernel<<<grid, block, 0, stream>>>(sre, sim, mre, mim, out);
}